// Round 1
// 128.367 us; speedup vs baseline: 1.0290x; 1.0290x over previous
//
#include <hip/hip_runtime.h>

// Shapes (fixed by the problem)
#define B_ 2
#define S_ 2048
#define D_ 1024
#define H_ 16
#define HS_ 64
#define HD_ 1024     // H_*HS_
#define BS_ (B_*S_)  // 4096 flattened rows
#define KS_ 64       // pipelined K-step (double-buffered)
#define TP_ 136      // padded row length (elems) for transposed LDS tiles

typedef __attribute__((ext_vector_type(8))) short short8_t;   // 8 bf16 (MFMA A/B frag)
typedef __attribute__((ext_vector_type(4))) float float4_t;   // MFMA C/D frag

__device__ inline unsigned short f32_to_bf16(float f) {
  unsigned int u = __float_as_uint(f);
  u += 0x7FFF + ((u >> 16) & 1);   // round-to-nearest-even
  return (unsigned short)(u >> 16);
}

// async global->LDS, 16B per lane. LDS dest is wave-uniform base + lane*16.
__device__ inline void async_copy16(const void* g, void* lds) {
  __builtin_amdgcn_global_load_lds(
      (const __attribute__((address_space(1))) void*)g,
      (__attribute__((address_space(3))) void*)lds, 16, 0, 0);
}

// XOR swizzle (8-chunk rows at KS_=64): LDS[row][phys chunk c] holds global
// chunk c ^ (row&7). Frag read of logical chunk q (=ks*4+quad, 0..7) from row
// R is at phys q ^ (R&7). Across a 16-lane group R&7 sweeps 8 values -> 32
// banks covered, 2 lanes/bank = free (m136). Same involution on both sides.

// ---------------------------------------------------------------------------
// prep: blocks [0,4096) convert x fp32->bf16 (4 elems/thread);
// blocks [4096,4352) build Wkvt[h][128][d] bf16 (rows 0-63 = Wk cols,
// rows 64-127 = Wv cols), k(d)-contiguous for kv_mfma B staging.
// ---------------------------------------------------------------------------
__global__ __launch_bounds__(256) void prep_kernel(
    const float* __restrict__ x, const float* __restrict__ Wk,
    const float* __restrict__ Wv, unsigned short* __restrict__ xb,
    unsigned short* __restrict__ Wkvt) {
  const int blk = blockIdx.x;
  const int tid = threadIdx.x;
  __shared__ float lds[64][65];
  if (blk < 4096) {
    int idx = blk * 256 + tid;
    float4 v = ((const float4*)x)[idx];
    ushort4 o;
    o.x = f32_to_bf16(v.x); o.y = f32_to_bf16(v.y);
    o.z = f32_to_bf16(v.z); o.w = f32_to_bf16(v.w);
    ((ushort4*)xb)[idx] = o;
    return;
  }
  const int wblk = blk - 4096;
  const int h = wblk >> 4;
  const int d0 = (wblk & 15) * 64;
  // K half
#pragma unroll
  for (int i = 0; i < 16; ++i) {
    int idx = tid + i * 256; int dd = idx >> 6, e = idx & 63;
    lds[e][dd] = Wk[((size_t)h * D_ + d0 + dd) * HS_ + e];
  }
  __syncthreads();
#pragma unroll
  for (int i = 0; i < 16; ++i) {
    int idx = tid + i * 256; int e = idx >> 6, dd = idx & 63;
    Wkvt[((size_t)h * 128 + e) * D_ + d0 + dd] = f32_to_bf16(lds[e][dd]);
  }
  __syncthreads();
  // V half
#pragma unroll
  for (int i = 0; i < 16; ++i) {
    int idx = tid + i * 256; int dd = idx >> 6, e = idx & 63;
    lds[e][dd] = Wv[((size_t)h * D_ + d0 + dd) * HS_ + e];
  }
  __syncthreads();
#pragma unroll
  for (int i = 0; i < 16; ++i) {
    int idx = tid + i * 256; int e = idx >> 6, dd = idx & 63;
    Wkvt[((size_t)h * 128 + 64 + e) * D_ + d0 + dd] = f32_to_bf16(lds[e][dd]);
  }
}

// ---------------------------------------------------------------------------
// kv_mfma (R7: T3/T4-lite pipeline): per (stile,h):
//   phase 1: [128 s x 128 (64 K | 64 V)] = x-tile @ Wkvt_h.
//     KS=64 double-buffered LDS (4x16KB=64KB), counted vmcnt(8) (never 0
//     mid-loop), raw s_barrier (no compiler vmcnt(0) drain), setprio on MFMA.
//   phase 2: LDS-transpose K,V -> Mpart[stile][h] = K^T V via MFMA; V
//            written to Vb. K never touches global memory.
// grid = 32*16 = 512 blocks (2/CU), 256 threads (4 waves as 2x2 of 64x64).
// ---------------------------------------------------------------------------
__global__ __launch_bounds__(256) void kv_mfma_kernel(
    const unsigned short* __restrict__ xb,    // [4096][1024]
    const unsigned short* __restrict__ Wkvt,  // [16][128][1024]
    unsigned short* __restrict__ Vb,          // [4096][1024]
    float* __restrict__ Mpart) {              // [32][16][64][64]
  const int blk = blockIdx.x;
  const int stile = blk & 31;
  const int h = blk >> 5;
  const int s0 = stile * 128;
  const int tid = threadIdx.x;
  const int lane = tid & 63;
  const int wid = tid >> 6;
  const int wm = wid & 1, wn = wid >> 1;
  const int quad = lane >> 4, l16 = lane & 15;
  const int srow8 = lane >> 3;               // 8 rows per copy instr (128B rows)
  const int sc8 = lane & 7;                  // phys 16B chunk within row
  const int xa = l16 & 7;                    // frag-read swizzle key

  // Double-buffered phase-1 LDS (64 KB); phase 2 aliases the front as
  // Ktl/Vtl transposed tiles [64][TP_] (34 KB).
  __shared__ __align__(16) unsigned char smem[65536];
  unsigned short* const A0 = (unsigned short*)smem;            // [0,16K)
  unsigned short* const B0 = (unsigned short*)(smem + 16384);  // [16K,32K)
  unsigned short* const A1 = (unsigned short*)(smem + 32768);  // [32K,48K)
  unsigned short* const B1 = (unsigned short*)(smem + 49152);  // [48K,64K)
  unsigned short* Ktl = (unsigned short*)smem;                 // [64][TP_]
  unsigned short* Vtl = (unsigned short*)(smem + 64 * TP_ * 2);

  float4_t acc[4][4];
  const float4_t fz = {0.f, 0.f, 0.f, 0.f};
#pragma unroll
  for (int i = 0; i < 4; ++i)
#pragma unroll
    for (int j = 0; j < 4; ++j) acc[i][j] = fz;

  // 8 async copies/thread per K-step: 4 A-groups + 4 B-groups of 8 rows.
  auto stage = [&](int kt, unsigned short* Ad, unsigned short* Bd) {
    const int k0 = kt * KS_;
#pragma unroll
    for (int i = 0; i < 4; ++i) {
      int g = wid * 4 + i;                 // 16 groups x 8 rows = 128 rows
      int r = g * 8 + srow8;
      int ch = (sc8 ^ (r & 7)) * 8;        // pre-swizzled global chunk (elems)
      async_copy16(xb + (size_t)(s0 + r) * D_ + k0 + ch, Ad + g * 8 * KS_);
      async_copy16(Wkvt + ((size_t)h * 128 + r) * D_ + k0 + ch, Bd + g * 8 * KS_);
    }
  };
  auto compute = [&](const unsigned short* Ac, const unsigned short* Bc) {
#pragma unroll
    for (int ks = 0; ks < 2; ++ks) {       // 2 k-slices of 32
      short8_t a[4], b[4];
#pragma unroll
      for (int mi = 0; mi < 4; ++mi)
        a[mi] = *(const short8_t*)(Ac + (wm * 64 + mi * 16 + l16) * KS_ +
                                   ((ks * 4 + quad) ^ xa) * 8);
#pragma unroll
      for (int ni = 0; ni < 4; ++ni)
        b[ni] = *(const short8_t*)(Bc + (wn * 64 + ni * 16 + l16) * KS_ +
                                   ((ks * 4 + quad) ^ xa) * 8);
      __builtin_amdgcn_s_setprio(1);
#pragma unroll
      for (int mi = 0; mi < 4; ++mi)
#pragma unroll
        for (int ni = 0; ni < 4; ++ni)
          acc[mi][ni] = __builtin_amdgcn_mfma_f32_16x16x32_bf16(
              a[mi], b[ni], acc[mi][ni], 0, 0, 0);
      __builtin_amdgcn_s_setprio(0);
    }
  };

  stage(0, A0, B0);
#pragma unroll
  for (int t = 0; t < 16; ++t) {
    unsigned short* Ac = (t & 1) ? A1 : A0;
    unsigned short* Bc = (t & 1) ? B1 : B0;
    if (t < 15) {
      stage(t + 1, (t & 1) ? A0 : A1, (t & 1) ? B0 : B1);
      // 16 outstanding (8 cur + 8 next); leave the 8 next-tile loads in flight.
      asm volatile("s_waitcnt vmcnt(8)" ::: "memory");
    } else {
      asm volatile("s_waitcnt vmcnt(0)" ::: "memory");
    }
    __builtin_amdgcn_s_barrier();          // all waves' cur-tile data landed
    __builtin_amdgcn_sched_barrier(0);
    compute(Ac, Bc);
    __builtin_amdgcn_sched_barrier(0);
    __builtin_amdgcn_s_barrier();          // WAR: cur fully read before re-stage
  }

  // ---- phase 2a: dump quadrants transposed into LDS (bf16) ----
  // C cols: wn==0 -> K features, wn==1 -> V features.
  {
    unsigned short* dstT = (wn == 0) ? Ktl : Vtl;
#pragma unroll
    for (int mi = 0; mi < 4; ++mi)
#pragma unroll
      for (int ni = 0; ni < 4; ++ni) {
        int f = ni * 16 + l16;
        int sm = wm * 64 + mi * 16 + quad * 4;
        ushort4 o;
        o.x = f32_to_bf16(acc[mi][ni][0]);
        o.y = f32_to_bf16(acc[mi][ni][1]);
        o.z = f32_to_bf16(acc[mi][ni][2]);
        o.w = f32_to_bf16(acc[mi][ni][3]);
        *(ushort4*)&dstT[f * TP_ + sm] = o;
      }
  }
  __syncthreads();

  // ---- phase 2b: Vb[s0+s][h*64+e] from Vtl (16B stores) ----
#pragma unroll
  for (int u = 0; u < 4; ++u) {
    int unit = tid + u * 256;            // 0..1023 = 128 s x 8 e-chunks
    int s = unit & 127;
    int ec = (unit >> 7) * 8;
    union { unsigned short u16[8]; uint4 v; } t;
#pragma unroll
    for (int e = 0; e < 8; ++e) t.u16[e] = Vtl[(ec + e) * TP_ + s];
    *(uint4*)&Vb[(size_t)(s0 + s) * HD_ + h * 64 + ec] = t.v;
  }

  // ---- phase 2c: Mpart[f][e] = sum_{s<128} K[s,f] V[s,e] via MFMA ----
  {
    float4_t macc[4];
#pragma unroll
    for (int ni = 0; ni < 4; ++ni) macc[ni] = fz;
#pragma unroll
    for (int ss = 0; ss < 4; ++ss) {     // 4 k-steps of 32 s
      short8_t ka = *(const short8_t*)&Ktl[(wid * 16 + l16) * TP_ + ss * 32 + quad * 8];
#pragma unroll
      for (int ni = 0; ni < 4; ++ni) {
        short8_t vv = *(const short8_t*)&Vtl[(ni * 16 + l16) * TP_ + ss * 32 + quad * 8];
        macc[ni] = __builtin_amdgcn_mfma_f32_16x16x32_bf16(ka, vv, macc[ni], 0, 0, 0);
      }
    }
    float* mdst = Mpart + ((size_t)stile * H_ + h) * 4096;
#pragma unroll
    for (int ni = 0; ni < 4; ++ni) {
      int e = ni * 16 + l16;
#pragma unroll
      for (int r = 0; r < 4; ++r) {
        int f = wid * 16 + quad * 4 + r;
        mdst[f * 64 + e] = macc[ni][r];
      }
    }
  }
}

// ---------------------------------------------------------------------------
// m_reduce: M[b,h] = 0.125 * sum over the 16 stiles of batch b. 128 blocks.
// ---------------------------------------------------------------------------
__global__ __launch_bounds__(256) void m_reduce_kernel(
    const float* __restrict__ Mpart, float* __restrict__ M) {
  const int gid = blockIdx.x * 256 + threadIdx.x;
  const int e0 = gid * 4;               // [0, 131072)
  const int bh = e0 >> 12;              // b*16+h
  const int idx = e0 & 4095;
  const int b = bh >> 4, h = bh & 15;
  float4 s = {0.f, 0.f, 0.f, 0.f};
#pragma unroll
  for (int p = 0; p < 16; ++p) {
    const float4 v =
        *(const float4*)&Mpart[(((size_t)(b * 16 + p)) * H_ + h) * 4096 + idx];
    s.x += v.x; s.y += v.y; s.z += v.z; s.w += v.w;
  }
  s.x *= 0.125f; s.y *= 0.125f; s.z *= 0.125f; s.w *= 0.125f;
  *(float4*)&M[(size_t)bh * 4096 + idx] = s;
}

// ---------------------------------------------------------------------------
// p_kernel: P[b][h*64+f][d] = sum_e M[b,h,f,e]*Wproj[h*64+e][d], written
// TRANSPOSED as Pt[b][d][h*64+f] bf16 (k-contiguous for out_mfma staging).
// grid = B*H*(D/64) = 512 blocks.
// ---------------------------------------------------------------------------
__global__ __launch_bounds__(256) void p_kernel(
    const float* __restrict__ M, const float* __restrict__ Wproj,
    unsigned short* __restrict__ Pt) {
  const int blk = blockIdx.x;
  const int dtile = blk & 15;
  const int h = (blk >> 4) & 15;
  const int b = blk >> 8;
  const int d0 = dtile * 64;
  const int tid = threadIdx.x;
  const int tx = tid & 15, ty = tid >> 4;
  __shared__ float Ms[64][68];  // A: [e][f] (transposed on store)
  __shared__ float Ws[64][68];  // B: [e][d]
  const size_t mbase = ((size_t)(b * H_ + h)) * HS_ * HS_;
#pragma unroll
  for (int i = 0; i < 16; ++i) {
    int idx = tid + i * 256;
    int f = idx >> 6, e = idx & 63;
    Ms[e][f] = M[mbase + idx];
    Ws[f][e] = Wproj[(size_t)(h * HS_ + f) * D_ + d0 + e];
  }
  __syncthreads();
  float acc[4][4] = {};
#pragma unroll
  for (int kk = 0; kk < 64; ++kk) {
    const float4 a4 = *(const float4*)&Ms[kk][ty * 4];
    const float4 b4 = *(const float4*)&Ws[kk][tx * 4];
    const float a[4] = {a4.x, a4.y, a4.z, a4.w};
    const float bb[4] = {b4.x, b4.y, b4.z, b4.w};
#pragma unroll
    for (int i = 0; i < 4; ++i)
#pragma unroll
      for (int j = 0; j < 4; ++j) acc[i][j] += a[i] * bb[j];
  }
  // transpose through LDS: trans[d][f] then linear bf16 rows
  __syncthreads();
#pragma unroll
  for (int i = 0; i < 4; ++i)
#pragma unroll
    for (int j = 0; j < 4; ++j)
      Ms[tx * 4 + j][ty * 4 + i] = acc[i][j];
  __syncthreads();
  {
    int c = tid >> 2, ch = tid & 3;  // row c (d-dim), 16-elem chunk of f-dim
    unsigned short* dst = Pt + ((size_t)(b * D_ + d0 + c)) * HD_ + h * 64 + ch * 16;
#pragma unroll
    for (int e = 0; e < 16; ++e) dst[e] = f32_to_bf16(Ms[c][ch * 16 + e]);
  }
}

// ---------------------------------------------------------------------------
// out_mfma (R7: same T3/T4-lite pipeline): out[s][d] = bproj[d] +
// sum_j Vb[s][j]*Pt[b][d][j]. 128x64 tiles, grid 512 (2/CU), KS=64
// double-buffered (48 KB), counted vmcnt(6), raw barriers, setprio.
// 4 waves as 2(m)x2(n), each wave 64x32.
// ---------------------------------------------------------------------------
__global__ __launch_bounds__(256) void out_mfma_kernel(
    const unsigned short* __restrict__ Vb,   // [4096][1024]
    const unsigned short* __restrict__ Pt,   // [2][1024][1024]
    const float* __restrict__ bproj,
    float* __restrict__ out) {
  const int blk = blockIdx.x;
  const int ntile = blk & 15;              // 1024/64 = 16
  const int stile = blk >> 4;              // 4096/128 = 32
  const int s0 = stile * 128;
  const int n0 = ntile * 64;
  const int b = s0 >> 11;
  const int tid = threadIdx.x;
  const int lane = tid & 63;
  const int wid = tid >> 6;
  const int wm = wid & 1, wn = wid >> 1;
  const int quad = lane >> 4, l16 = lane & 15;
  const int srow8 = lane >> 3;             // 8 rows per copy instr (128B rows)
  const int sc8 = lane & 7;
  const int xa = l16 & 7;

  __shared__ __align__(16) unsigned char smem[49152];
  unsigned short* const A0 = (unsigned short*)smem;            // 16 KB
  unsigned short* const B0 = (unsigned short*)(smem + 16384);  // 8 KB
  unsigned short* const A1 = (unsigned short*)(smem + 24576);  // 16 KB
  unsigned short* const B1 = (unsigned short*)(smem + 40960);  // 8 KB

  float4_t acc[4][2];
  const float4_t fz = {0.f, 0.f, 0.f, 0.f};
#pragma unroll
  for (int i = 0; i < 4; ++i)
#pragma unroll
    for (int j = 0; j < 2; ++j) acc[i][j] = fz;

  const unsigned short* Bpanel = Pt + (size_t)b * D_ * HD_;
  // 6 async copies/thread per K-step: 4 A-groups + 2 B-groups of 8 rows.
  auto stage = [&](int kt, unsigned short* Ad, unsigned short* Bd) {
    const int k0 = kt * KS_;
#pragma unroll
    for (int i = 0; i < 4; ++i) {          // A: 16 groups x 8 rows = 128
      int g = wid * 4 + i;
      int r = g * 8 + srow8;
      int ch = (sc8 ^ (r & 7)) * 8;
      async_copy16(Vb + (size_t)(s0 + r) * HD_ + k0 + ch, Ad + g * 8 * KS_);
    }
#pragma unroll
    for (int i = 0; i < 2; ++i) {          // B: 8 groups x 8 rows = 64
      int g = wid * 2 + i;
      int r = g * 8 + srow8;
      int ch = (sc8 ^ (r & 7)) * 8;
      async_copy16(Bpanel + (size_t)(n0 + r) * HD_ + k0 + ch, Bd + g * 8 * KS_);
    }
  };
  auto compute = [&](const unsigned short* Ac, const unsigned short* Bc) {
#pragma unroll
    for (int ks = 0; ks < 2; ++ks) {
      short8_t a[4], bfr[2];
#pragma unroll
      for (int mi = 0; mi < 4; ++mi)
        a[mi] = *(const short8_t*)(Ac + (wm * 64 + mi * 16 + l16) * KS_ +
                                   ((ks * 4 + quad) ^ xa) * 8);
#pragma unroll
      for (int ni = 0; ni < 2; ++ni)
        bfr[ni] = *(const short8_t*)(Bc + (wn * 32 + ni * 16 + l16) * KS_ +
                                     ((ks * 4 + quad) ^ xa) * 8);
      __builtin_amdgcn_s_setprio(1);
#pragma unroll
      for (int mi = 0; mi < 4; ++mi)
#pragma unroll
        for (int ni = 0; ni < 2; ++ni)
          acc[mi][ni] = __builtin_amdgcn_mfma_f32_16x16x32_bf16(
              a[mi], bfr[ni], acc[mi][ni], 0, 0, 0);
      __builtin_amdgcn_s_setprio(0);
    }
  };

  stage(0, A0, B0);
#pragma unroll
  for (int t = 0; t < 16; ++t) {
    unsigned short* Ac = (t & 1) ? A1 : A0;
    unsigned short* Bc = (t & 1) ? B1 : B0;
    if (t < 15) {
      stage(t + 1, (t & 1) ? A0 : A1, (t & 1) ? B0 : B1);
      // 12 outstanding (6 cur + 6 next); keep the 6 next-tile loads in flight.
      asm volatile("s_waitcnt vmcnt(6)" ::: "memory");
    } else {
      asm volatile("s_waitcnt vmcnt(0)" ::: "memory");
    }
    __builtin_amdgcn_s_barrier();
    __builtin_amdgcn_sched_barrier(0);
    compute(Ac, Bc);
    __builtin_amdgcn_sched_barrier(0);
    __builtin_amdgcn_s_barrier();
  }

#pragma unroll
  for (int ni = 0; ni < 2; ++ni) {
    int col = n0 + wn * 32 + ni * 16 + l16;
    float bias = bproj[col];
#pragma unroll
    for (int mi = 0; mi < 4; ++mi) {
      int rowb = s0 + wm * 64 + mi * 16 + quad * 4;
#pragma unroll
      for (int r = 0; r < 4; ++r)
        out[(size_t)(rowb + r) * D_ + col] = acc[mi][ni][r] + bias;
    }
  }
}

extern "C" void kernel_launch(void* const* d_in, const int* in_sizes, int n_in,
                              void* d_out, int out_size, void* d_ws, size_t ws_size,
                              hipStream_t stream) {
  const float* x = (const float*)d_in[0];
  const float* Wk = (const float*)d_in[1];
  const float* Wv = (const float*)d_in[2];
  const float* Wproj = (const float*)d_in[3];
  const float* bproj = (const float*)d_in[4];
  float* out = (float*)d_out;

  // Workspace layout (~32.5 MB total); every element written before read.
  char* ws = (char*)d_ws;
  unsigned short* xb = (unsigned short*)ws;                  // 4M bf16 = 8 MB
  unsigned short* Wkvt = xb + (size_t)BS_ * D_;              // 2M bf16 = 4 MB
  unsigned short* Vb = Wkvt + (size_t)H_ * 128 * D_;         // 4M bf16 = 8 MB
  float* Mpart = (float*)(Vb + (size_t)BS_ * HD_);           // 2M f32 = 8 MB  [32][16][4096]
  float* M = Mpart + (size_t)32 * H_ * 4096;                 // 128K f32 = 0.5 MB
  unsigned short* Pt = (unsigned short*)(M + (size_t)B_ * H_ * 4096);  // 2M bf16 = 4 MB

  prep_kernel<<<dim3(4096 + H_ * (D_ / 64)), dim3(256), 0, stream>>>(x, Wk, Wv, xb, Wkvt);
  kv_mfma_kernel<<<dim3(32 * H_), dim3(256), 0, stream>>>(xb, Wkvt, Vb, Mpart);
  m_reduce_kernel<<<dim3(128), dim3(256), 0, stream>>>(Mpart, M);
  p_kernel<<<dim3(B_ * H_ * (D_ / 64)), dim3(256), 0, stream>>>(M, Wproj, Pt);
  out_mfma_kernel<<<dim3(32 * 16), dim3(256), 0, stream>>>(Vb, Pt, bproj, out);
}